// Round 1
// baseline (1057.113 us; speedup 1.0000x reference)
//
#include <hip/hip_runtime.h>

#define D 128
#define TILE_M 128
#define TILE_K 32

// ---------------- CSR build ----------------

__global__ void hist_kernel(const int* __restrict__ dst, int* __restrict__ deg, int E) {
    int e = blockIdx.x * 256 + threadIdx.x;
    if (e < E) atomicAdd(&deg[dst[e]], 1);
}

__global__ void dis_kernel(const int* __restrict__ deg, float* __restrict__ dis, int N) {
    int n = blockIdx.x * 256 + threadIdx.x;
    if (n < N) dis[n] = rsqrtf((float)deg[n] + 1.0f);
}

// chunk sums: each block reduces 1024 ints
__global__ void scan1_kernel(const int* __restrict__ deg, int* __restrict__ csum, int N) {
    __shared__ int lds[256];
    int t = threadIdx.x;
    int base = blockIdx.x * 1024 + t * 4;
    int s = 0;
#pragma unroll
    for (int i = 0; i < 4; i++) { int j = base + i; if (j < N) s += deg[j]; }
    lds[t] = s;
    __syncthreads();
    for (int off = 128; off > 0; off >>= 1) {
        if (t < off) lds[t] += lds[t + off];
        __syncthreads();
    }
    if (t == 0) csum[blockIdx.x] = lds[0];
}

// exclusive scan of chunk sums (B ~ 98, trivial serial)
__global__ void scan2_kernel(int* __restrict__ csum, int B) {
    if (blockIdx.x == 0 && threadIdx.x == 0) {
        int acc = 0;
        for (int i = 0; i < B; i++) { int v = csum[i]; csum[i] = acc; acc += v; }
    }
}

// per-chunk exclusive scan + chunk offset -> row offsets, also init cursor
__global__ void scan3_kernel(const int* __restrict__ deg, const int* __restrict__ csum,
                             int* __restrict__ offs, int* __restrict__ cursor, int N, int E) {
    __shared__ int lds[256];
    int t = threadIdx.x;
    int base = blockIdx.x * 1024 + t * 4;
    int v[4]; int s = 0;
#pragma unroll
    for (int i = 0; i < 4; i++) { int j = base + i; v[i] = (j < N) ? deg[j] : 0; s += v[i]; }
    lds[t] = s;
    __syncthreads();
    // Hillis-Steele inclusive scan over 256 thread sums
    for (int off = 1; off < 256; off <<= 1) {
        int x = (t >= off) ? lds[t - off] : 0;
        __syncthreads();
        lds[t] += x;
        __syncthreads();
    }
    int excl = lds[t] - s + csum[blockIdx.x];
#pragma unroll
    for (int i = 0; i < 4; i++) {
        int j = base + i;
        if (j < N) { offs[j] = excl; cursor[j] = excl; excl += v[i]; }
    }
    if (blockIdx.x == 0 && t == 0) offs[N] = E;
}

__global__ void scatter_kernel(const int* __restrict__ src, const int* __restrict__ dst,
                               int* __restrict__ cursor, int* __restrict__ csr_src, int E) {
    int e = blockIdx.x * 256 + threadIdx.x;
    if (e < E) {
        int p = atomicAdd(&cursor[dst[e]], 1);
        csr_src[p] = src[e];
    }
}

// ---------------- GEMM: U = (A @ W) * dis[row] ----------------
// A: [N,128] row-major, W: [128,128] row-major (k,c). fp32 vector-ALU tiled GEMM.
__launch_bounds__(256)
__global__ void gemm_scale_kernel(const float* __restrict__ A, const float* __restrict__ W,
                                  const float* __restrict__ dis, float* __restrict__ U, int N) {
    __shared__ float a_lds[TILE_K][TILE_M + 4];  // [k][row], padded
    __shared__ float w_lds[TILE_K][D + 4];       // [k][col], padded
    int tid = threadIdx.x;
    int m0 = blockIdx.x * TILE_M;
    int tr = (tid >> 4) * 8;   // 16 row-groups of 8
    int tc = (tid & 15) * 8;   // 16 col-groups of 8
    float acc[8][8] = {};

    for (int k0 = 0; k0 < D; k0 += TILE_K) {
        // stage W chunk [32 x 128]: 1024 float4 via 256 threads
        for (int i = tid; i < TILE_K * 32; i += 256) {
            int kk = i >> 5; int cc = (i & 31) << 2;
            float4 wv = *(const float4*)&W[(k0 + kk) * D + cc];
            w_lds[kk][cc] = wv.x; w_lds[kk][cc + 1] = wv.y;
            w_lds[kk][cc + 2] = wv.z; w_lds[kk][cc + 3] = wv.w;
        }
        // stage A chunk [128 rows x 32 k] transposed to [k][row]
        for (int i = tid; i < 1024; i += 256) {
            int r = i >> 3; int kk = (i & 7) << 2;
            int row = m0 + r;
            float4 av = (row < N) ? *(const float4*)&A[(size_t)row * D + k0 + kk]
                                  : make_float4(0.f, 0.f, 0.f, 0.f);
            a_lds[kk + 0][r] = av.x; a_lds[kk + 1][r] = av.y;
            a_lds[kk + 2][r] = av.z; a_lds[kk + 3][r] = av.w;
        }
        __syncthreads();
#pragma unroll 8
        for (int k = 0; k < TILE_K; k++) {
            float a[8], b[8];
            *(float4*)&a[0] = *(float4*)&a_lds[k][tr];
            *(float4*)&a[4] = *(float4*)&a_lds[k][tr + 4];
            *(float4*)&b[0] = *(float4*)&w_lds[k][tc];
            *(float4*)&b[4] = *(float4*)&w_lds[k][tc + 4];
#pragma unroll
            for (int i = 0; i < 8; i++)
#pragma unroll
                for (int j = 0; j < 8; j++)
                    acc[i][j] = fmaf(a[i], b[j], acc[i][j]);
        }
        __syncthreads();
    }
#pragma unroll
    for (int i = 0; i < 8; i++) {
        int row = m0 + tr + i;
        if (row < N) {
            float s = dis[row];
            float o[8];
#pragma unroll
            for (int j = 0; j < 8; j++) o[j] = acc[i][j] * s;
            *(float4*)&U[(size_t)row * D + tc] = *(float4*)&o[0];
            *(float4*)&U[(size_t)row * D + tc + 4] = *(float4*)&o[4];
        }
    }
}

// ---------------- Aggregation: H[n] = relu(dis[n]*(U[n] + sum_in U[src]) + b) ----------------
__global__ void aggregate_kernel(const float* __restrict__ U, const int* __restrict__ offs,
                                 const int* __restrict__ csr_src, const float* __restrict__ dis,
                                 const float* __restrict__ bias, float* __restrict__ H, int N) {
    int n = blockIdx.x;
    int c = threadIdx.x;
    float acc = U[(size_t)n * D + c];  // self-loop term (u[n])
    int s = offs[n], e = offs[n + 1];
    for (int i = s; i < e; i++) {
        int src = csr_src[i];
        acc += U[(size_t)src * D + c];
    }
    float v = fmaf(acc, dis[n], bias[c]);
    H[(size_t)n * D + c] = fmaxf(v, 0.0f);
}

// ---------------- Mean-pool per graph + FC ----------------
__global__ void pool_fc_kernel(const float* __restrict__ H, const int* __restrict__ batch,
                               const float* __restrict__ Wfc, const float* __restrict__ bfc,
                               float* __restrict__ out, int N) {
    int g = blockIdx.x;
    int c = threadIdx.x;
    // lower_bound(g) and lower_bound(g+1) in sorted batch (all threads same path -> broadcast)
    int lo = 0, hi = N;
    while (lo < hi) { int mid = (lo + hi) >> 1; if (batch[mid] < g) lo = mid + 1; else hi = mid; }
    int st = lo;
    hi = N;
    while (lo < hi) { int mid = (lo + hi) >> 1; if (batch[mid] < g + 1) lo = mid + 1; else hi = mid; }
    int en = lo;
    float sum = 0.f;
    for (int i = st; i < en; i++) sum += H[(size_t)i * D + c];
    float cnt = (float)(en - st);
    if (cnt < 1.f) cnt = 1.f;
    float p = (sum / cnt) * Wfc[c];
    // reduce 128 lanes -> scalar (2 waves)
    for (int off = 32; off > 0; off >>= 1) p += __shfl_down(p, off);
    __shared__ float red[2];
    if ((c & 63) == 0) red[c >> 6] = p;
    __syncthreads();
    if (c == 0) out[g] = red[0] + red[1] + bfc[0];
}

extern "C" void kernel_launch(void* const* d_in, const int* in_sizes, int n_in,
                              void* d_out, int out_size, void* d_ws, size_t ws_size,
                              hipStream_t stream) {
    const float* x   = (const float*)d_in[0];
    const int* eidx  = (const int*)d_in[1];
    const int* batch = (const int*)d_in[2];
    const float* W1  = (const float*)d_in[3];
    const float* b1  = (const float*)d_in[4];
    const float* W2  = (const float*)d_in[5];
    const float* b2  = (const float*)d_in[6];
    const float* W3  = (const float*)d_in[7];
    const float* b3  = (const float*)d_in[8];
    const float* Wfc = (const float*)d_in[9];
    const float* bfc = (const float*)d_in[10];
    float* out = (float*)d_out;

    int N = in_sizes[2];
    int E = in_sizes[1] / 2;
    int G = out_size;

    const int* src = eidx;
    const int* dst = eidx + E;

    // bump allocator on workspace
    char* ws = (char*)d_ws;
    size_t off = 0;
    auto alloc = [&](size_t bytes) -> void* {
        void* p = ws + off;
        off += (bytes + 255) & ~(size_t)255;
        return p;
    };
    float* U    = (float*)alloc((size_t)N * D * sizeof(float));
    float* H    = (float*)alloc((size_t)N * D * sizeof(float));
    float* dis  = (float*)alloc((size_t)N * sizeof(float));
    int* deg    = (int*)alloc((size_t)N * sizeof(int));
    int* offs   = (int*)alloc((size_t)(N + 1) * sizeof(int));
    int* cursor = (int*)alloc((size_t)N * sizeof(int));
    int* csr    = (int*)alloc((size_t)E * sizeof(int));
    int* csum   = (int*)alloc(4096);
    (void)ws_size; (void)n_in;

    hipMemsetAsync(deg, 0, (size_t)N * sizeof(int), stream);

    int eb = (E + 255) / 256;
    int nb = (N + 255) / 256;
    int B1 = (N + 1023) / 1024;

    hist_kernel<<<eb, 256, 0, stream>>>(dst, deg, E);
    dis_kernel<<<nb, 256, 0, stream>>>(deg, dis, N);
    scan1_kernel<<<B1, 256, 0, stream>>>(deg, csum, N);
    scan2_kernel<<<1, 64, 0, stream>>>(csum, B1);
    scan3_kernel<<<B1, 256, 0, stream>>>(deg, csum, offs, cursor, N, E);
    scatter_kernel<<<eb, 256, 0, stream>>>(src, dst, cursor, csr, E);

    int gb = (N + TILE_M - 1) / TILE_M;

    gemm_scale_kernel<<<gb, 256, 0, stream>>>(x, W1, dis, U, N);
    aggregate_kernel<<<N, 128, 0, stream>>>(U, offs, csr, dis, b1, H, N);
    gemm_scale_kernel<<<gb, 256, 0, stream>>>(H, W2, dis, U, N);
    aggregate_kernel<<<N, 128, 0, stream>>>(U, offs, csr, dis, b2, H, N);
    gemm_scale_kernel<<<gb, 256, 0, stream>>>(H, W3, dis, U, N);
    aggregate_kernel<<<N, 128, 0, stream>>>(U, offs, csr, dis, b3, H, N);
    pool_fc_kernel<<<G, 128, 0, stream>>>(H, batch, Wfc, bfc, out, N);
}

// Round 2
// 775.207 us; speedup vs baseline: 1.3637x; 1.3637x over previous
//
#include <hip/hip_runtime.h>

#define D 128
#define TILE_M 128
#define TILE_K 32

typedef unsigned int uint;
typedef unsigned short ushort;

// ---- bf16 helpers (manual, RNE) ----
__device__ __forceinline__ float bf_lo(uint u) { return __uint_as_float(u << 16); }
__device__ __forceinline__ float bf_hi(uint u) { return __uint_as_float(u & 0xffff0000u); }
__device__ __forceinline__ uint f2bf(float f) {
    uint x = __float_as_uint(f);
    return (x + 0x7fffu + ((x >> 16) & 1u)) >> 16;  // RNE
}

// ---------------- CSR build ----------------

__global__ void hist_kernel(const int* __restrict__ dst, int* __restrict__ deg, int E) {
    int e = blockIdx.x * 256 + threadIdx.x;
    if (e < E) atomicAdd(&deg[dst[e]], 1);
}

__global__ void dis_kernel(const int* __restrict__ deg, float* __restrict__ dis, int N) {
    int n = blockIdx.x * 256 + threadIdx.x;
    if (n < N) dis[n] = rsqrtf((float)deg[n] + 1.0f);
}

__global__ void scan1_kernel(const int* __restrict__ deg, int* __restrict__ csum, int N) {
    __shared__ int lds[256];
    int t = threadIdx.x;
    int base = blockIdx.x * 1024 + t * 4;
    int s = 0;
#pragma unroll
    for (int i = 0; i < 4; i++) { int j = base + i; if (j < N) s += deg[j]; }
    lds[t] = s;
    __syncthreads();
    for (int off = 128; off > 0; off >>= 1) {
        if (t < off) lds[t] += lds[t + off];
        __syncthreads();
    }
    if (t == 0) csum[blockIdx.x] = lds[0];
}

__global__ void scan2_kernel(int* __restrict__ csum, int B) {
    if (blockIdx.x == 0 && threadIdx.x == 0) {
        int acc = 0;
        for (int i = 0; i < B; i++) { int v = csum[i]; csum[i] = acc; acc += v; }
    }
}

__global__ void scan3_kernel(const int* __restrict__ deg, const int* __restrict__ csum,
                             int* __restrict__ offs, int* __restrict__ cursor, int N, int E) {
    __shared__ int lds[256];
    int t = threadIdx.x;
    int base = blockIdx.x * 1024 + t * 4;
    int v[4]; int s = 0;
#pragma unroll
    for (int i = 0; i < 4; i++) { int j = base + i; v[i] = (j < N) ? deg[j] : 0; s += v[i]; }
    lds[t] = s;
    __syncthreads();
    for (int off = 1; off < 256; off <<= 1) {
        int x = (t >= off) ? lds[t - off] : 0;
        __syncthreads();
        lds[t] += x;
        __syncthreads();
    }
    int excl = lds[t] - s + csum[blockIdx.x];
#pragma unroll
    for (int i = 0; i < 4; i++) {
        int j = base + i;
        if (j < N) { offs[j] = excl; cursor[j] = excl; excl += v[i]; }
    }
    if (blockIdx.x == 0 && t == 0) offs[N] = E;
}

__global__ void scatter_kernel(const int* __restrict__ src, const int* __restrict__ dst,
                               int* __restrict__ cursor, int* __restrict__ csr_src, int E) {
    int e = blockIdx.x * 256 + threadIdx.x;
    if (e < E) {
        int p = atomicAdd(&cursor[dst[e]], 1);
        csr_src[p] = src[e];
    }
}

// ---------------- GEMM: U = bf16( (A @ W) * dis[row] ) ----------------
// A: [N,128] fp32 row-major, W: [128,128] fp32. fp32 math, bf16 store.
__launch_bounds__(256)
__global__ void gemm_scale_kernel(const float* __restrict__ A, const float* __restrict__ W,
                                  const float* __restrict__ dis, uint* __restrict__ U, int N) {
    __shared__ float a_lds[TILE_K][TILE_M + 4];
    __shared__ float w_lds[TILE_K][D + 4];
    int tid = threadIdx.x;
    int m0 = blockIdx.x * TILE_M;
    int tr = (tid >> 4) * 8;
    int tc = (tid & 15) * 8;
    float acc[8][8] = {};

    for (int k0 = 0; k0 < D; k0 += TILE_K) {
        for (int i = tid; i < TILE_K * 32; i += 256) {
            int kk = i >> 5; int cc = (i & 31) << 2;
            float4 wv = *(const float4*)&W[(k0 + kk) * D + cc];
            w_lds[kk][cc] = wv.x; w_lds[kk][cc + 1] = wv.y;
            w_lds[kk][cc + 2] = wv.z; w_lds[kk][cc + 3] = wv.w;
        }
        for (int i = tid; i < 1024; i += 256) {
            int r = i >> 3; int kk = (i & 7) << 2;
            int row = m0 + r;
            float4 av = (row < N) ? *(const float4*)&A[(size_t)row * D + k0 + kk]
                                  : make_float4(0.f, 0.f, 0.f, 0.f);
            a_lds[kk + 0][r] = av.x; a_lds[kk + 1][r] = av.y;
            a_lds[kk + 2][r] = av.z; a_lds[kk + 3][r] = av.w;
        }
        __syncthreads();
#pragma unroll 8
        for (int k = 0; k < TILE_K; k++) {
            float a[8], b[8];
            *(float4*)&a[0] = *(float4*)&a_lds[k][tr];
            *(float4*)&a[4] = *(float4*)&a_lds[k][tr + 4];
            *(float4*)&b[0] = *(float4*)&w_lds[k][tc];
            *(float4*)&b[4] = *(float4*)&w_lds[k][tc + 4];
#pragma unroll
            for (int i = 0; i < 8; i++)
#pragma unroll
                for (int j = 0; j < 8; j++)
                    acc[i][j] = fmaf(a[i], b[j], acc[i][j]);
        }
        __syncthreads();
    }
#pragma unroll
    for (int i = 0; i < 8; i++) {
        int row = m0 + tr + i;
        if (row < N) {
            float s = dis[row];
            uint4 pk;
            pk.x = f2bf(acc[i][0] * s) | (f2bf(acc[i][1] * s) << 16);
            pk.y = f2bf(acc[i][2] * s) | (f2bf(acc[i][3] * s) << 16);
            pk.z = f2bf(acc[i][4] * s) | (f2bf(acc[i][5] * s) << 16);
            pk.w = f2bf(acc[i][6] * s) | (f2bf(acc[i][7] * s) << 16);
            // U row = 64 uints (128 bf16); cols tc..tc+7 -> uint idx tc/2..tc/2+3
            *(uint4*)&U[(size_t)row * 64 + (tc >> 1)] = pk;
        }
    }
}

// ---------------- Aggregation: H[n] = relu(dis[n]*(u[n] + sum_in u[src]) + b) ----------------
// One wave (64 lanes) per node; lane handles 2 channels (one uint = 2 bf16).
__launch_bounds__(256)
__global__ void aggregate_kernel(const uint* __restrict__ U, const int* __restrict__ offs,
                                 const int* __restrict__ csr_src, const float* __restrict__ dis,
                                 const float* __restrict__ bias, float* __restrict__ H, int N) {
    int wave = threadIdx.x >> 6;
    int lane = threadIdx.x & 63;
    int n = blockIdx.x * 4 + wave;
    if (n >= N) return;

    uint self = U[(size_t)n * 64 + lane];
    float accx = bf_lo(self);
    float accy = bf_hi(self);

    int s = offs[n], e = offs[n + 1];
    int i = s;
    for (; i + 3 < e; i += 4) {
        int s0 = csr_src[i], s1 = csr_src[i + 1], s2 = csr_src[i + 2], s3 = csr_src[i + 3];
        uint u0 = U[(size_t)s0 * 64 + lane];
        uint u1 = U[(size_t)s1 * 64 + lane];
        uint u2 = U[(size_t)s2 * 64 + lane];
        uint u3 = U[(size_t)s3 * 64 + lane];
        accx += bf_lo(u0) + bf_lo(u1) + bf_lo(u2) + bf_lo(u3);
        accy += bf_hi(u0) + bf_hi(u1) + bf_hi(u2) + bf_hi(u3);
    }
    for (; i < e; i++) {
        uint u = U[(size_t)csr_src[i] * 64 + lane];
        accx += bf_lo(u);
        accy += bf_hi(u);
    }

    float dn = dis[n];
    float2 b = *(const float2*)&bias[lane * 2];
    float2 o;
    o.x = fmaxf(fmaf(accx, dn, b.x), 0.0f);
    o.y = fmaxf(fmaf(accy, dn, b.y), 0.0f);
    *(float2*)&H[(size_t)n * D + lane * 2] = o;
}

// ---------------- Mean-pool per graph + FC ----------------
__global__ void pool_fc_kernel(const float* __restrict__ H, const int* __restrict__ batch,
                               const float* __restrict__ Wfc, const float* __restrict__ bfc,
                               float* __restrict__ out, int N) {
    int g = blockIdx.x;
    int c = threadIdx.x;
    int lo = 0, hi = N;
    while (lo < hi) { int mid = (lo + hi) >> 1; if (batch[mid] < g) lo = mid + 1; else hi = mid; }
    int st = lo;
    hi = N;
    while (lo < hi) { int mid = (lo + hi) >> 1; if (batch[mid] < g + 1) lo = mid + 1; else hi = mid; }
    int en = lo;
    float sum = 0.f;
    for (int i = st; i < en; i++) sum += H[(size_t)i * D + c];
    float cnt = (float)(en - st);
    if (cnt < 1.f) cnt = 1.f;
    float p = (sum / cnt) * Wfc[c];
    for (int off = 32; off > 0; off >>= 1) p += __shfl_down(p, off);
    __shared__ float red[2];
    if ((c & 63) == 0) red[c >> 6] = p;
    __syncthreads();
    if (c == 0) out[g] = red[0] + red[1] + bfc[0];
}

extern "C" void kernel_launch(void* const* d_in, const int* in_sizes, int n_in,
                              void* d_out, int out_size, void* d_ws, size_t ws_size,
                              hipStream_t stream) {
    const float* x   = (const float*)d_in[0];
    const int* eidx  = (const int*)d_in[1];
    const int* batch = (const int*)d_in[2];
    const float* W1  = (const float*)d_in[3];
    const float* b1  = (const float*)d_in[4];
    const float* W2  = (const float*)d_in[5];
    const float* b2  = (const float*)d_in[6];
    const float* W3  = (const float*)d_in[7];
    const float* b3  = (const float*)d_in[8];
    const float* Wfc = (const float*)d_in[9];
    const float* bfc = (const float*)d_in[10];
    float* out = (float*)d_out;

    int N = in_sizes[2];
    int E = in_sizes[1] / 2;
    int G = out_size;

    const int* src = eidx;
    const int* dst = eidx + E;

    char* ws = (char*)d_ws;
    size_t off = 0;
    auto alloc = [&](size_t bytes) -> void* {
        void* p = ws + off;
        off += (bytes + 255) & ~(size_t)255;
        return p;
    };
    uint* U     = (uint*)alloc((size_t)N * 64 * sizeof(uint));    // bf16 [N,128]
    float* H    = (float*)alloc((size_t)N * D * sizeof(float));
    float* dis  = (float*)alloc((size_t)N * sizeof(float));
    int* deg    = (int*)alloc((size_t)N * sizeof(int));
    int* offs   = (int*)alloc((size_t)(N + 1) * sizeof(int));
    int* cursor = (int*)alloc((size_t)N * sizeof(int));
    int* csr    = (int*)alloc((size_t)E * sizeof(int));
    int* csum   = (int*)alloc(4096);
    (void)ws_size; (void)n_in;

    hipMemsetAsync(deg, 0, (size_t)N * sizeof(int), stream);

    int eb = (E + 255) / 256;
    int nb = (N + 255) / 256;
    int B1 = (N + 1023) / 1024;

    hist_kernel<<<eb, 256, 0, stream>>>(dst, deg, E);
    dis_kernel<<<nb, 256, 0, stream>>>(deg, dis, N);
    scan1_kernel<<<B1, 256, 0, stream>>>(deg, csum, N);
    scan2_kernel<<<1, 64, 0, stream>>>(csum, B1);
    scan3_kernel<<<B1, 256, 0, stream>>>(deg, csum, offs, cursor, N, E);
    scatter_kernel<<<eb, 256, 0, stream>>>(src, dst, cursor, csr, E);

    int gb = (N + TILE_M - 1) / TILE_M;
    int ab = (N + 3) / 4;

    gemm_scale_kernel<<<gb, 256, 0, stream>>>(x, W1, dis, U, N);
    aggregate_kernel<<<ab, 256, 0, stream>>>(U, offs, csr, dis, b1, H, N);
    gemm_scale_kernel<<<gb, 256, 0, stream>>>(H, W2, dis, U, N);
    aggregate_kernel<<<ab, 256, 0, stream>>>(U, offs, csr, dis, b2, H, N);
    gemm_scale_kernel<<<gb, 256, 0, stream>>>(H, W3, dis, U, N);
    aggregate_kernel<<<ab, 256, 0, stream>>>(U, offs, csr, dis, b3, H, N);
    pool_fc_kernel<<<G, 128, 0, stream>>>(H, batch, Wfc, bfc, out, N);
}

// Round 3
// 642.102 us; speedup vs baseline: 1.6463x; 1.2073x over previous
//
#include <hip/hip_runtime.h>

#define D 128
#define TILE_M 128
#define TILE_K 32

typedef unsigned int uint;
typedef unsigned short ushort;

// ---- bf16 helpers (manual, RNE) ----
__device__ __forceinline__ float bf_lo(uint u) { return __uint_as_float(u << 16); }
__device__ __forceinline__ float bf_hi(uint u) { return __uint_as_float(u & 0xffff0000u); }
__device__ __forceinline__ uint f2bf(float f) {
    uint x = __float_as_uint(f);
    return (x + 0x7fffu + ((x >> 16) & 1u)) >> 16;  // RNE
}

// ================= Bucketed CSR build =================
// bucket = dst >> 10 (1024 nodes/bucket, NB = ceil(N/1024) <= 128)
// binned entry = src | (local_dst << 17)   (src < 2^17, local < 2^10)

#define CHUNK 4096

__global__ void bucket_count_kernel(const int* __restrict__ dst, int* __restrict__ g_cnt, int E) {
    __shared__ int cnt[128];
    int t = threadIdx.x;
    if (t < 128) cnt[t] = 0;
    __syncthreads();
    int s0 = blockIdx.x * CHUNK;
    int e0 = min(s0 + CHUNK, E);
    for (int e = s0 + t; e < e0; e += 256)
        atomicAdd(&cnt[dst[e] >> 10], 1);
    __syncthreads();
    if (t < 128 && cnt[t]) atomicAdd(&g_cnt[t], cnt[t]);
}

__global__ void bucket_scan_kernel(const int* __restrict__ g_cnt, int* __restrict__ base,
                                   int* __restrict__ cursor, int NB) {
    if (threadIdx.x == 0 && blockIdx.x == 0) {
        int acc = 0;
        for (int i = 0; i < NB; i++) {
            base[i] = acc; cursor[i] = acc; acc += g_cnt[i];
        }
        base[NB] = acc;
    }
}

__global__ void bin_kernel(const int* __restrict__ src, const int* __restrict__ dst,
                           int* __restrict__ cursor, uint* __restrict__ binned, int E) {
    __shared__ int cnt[128];
    __shared__ int wcur[128];
    int t = threadIdx.x;
    if (t < 128) cnt[t] = 0;
    __syncthreads();
    int s0 = blockIdx.x * CHUNK;
    int e0 = min(s0 + CHUNK, E);
    for (int e = s0 + t; e < e0; e += 256)
        atomicAdd(&cnt[dst[e] >> 10], 1);
    __syncthreads();
    if (t < 128) {
        int c = cnt[t];
        wcur[t] = c ? atomicAdd(&cursor[t], c) : 0;
    }
    __syncthreads();
    for (int e = s0 + t; e < e0; e += 256) {
        int d = dst[e];
        int b = d >> 10;
        int p = atomicAdd(&wcur[b], 1);
        binned[p] = (uint)src[e] | ((uint)(d & 1023) << 17);
    }
}

// one block per bucket: local hist -> scan -> offs/dis write -> windowed csr scatter
__launch_bounds__(256)
__global__ void bucket_build_kernel(const uint* __restrict__ binned, const int* __restrict__ base,
                                    int* __restrict__ offs, int* __restrict__ csr,
                                    float* __restrict__ dis, int N, int E) {
    __shared__ int hist[1024];
    __shared__ int tsum[256];
    __shared__ int wcur[1024];
    int b = blockIdx.x;
    int t = threadIdx.x;
    int s = base[b], e = base[b + 1];
    for (int i = t; i < 1024; i += 256) hist[i] = 0;
    __syncthreads();
    for (int i = s + t; i < e; i += 256)
        atomicAdd(&hist[(binned[i] >> 17) & 1023], 1);
    __syncthreads();
    int h0 = t * 4;
    int v0 = hist[h0], v1 = hist[h0 + 1], v2 = hist[h0 + 2], v3 = hist[h0 + 3];
    int ts = v0 + v1 + v2 + v3;
    tsum[t] = ts;
    __syncthreads();
    for (int off = 1; off < 256; off <<= 1) {
        int x = (t >= off) ? tsum[t - off] : 0;
        __syncthreads();
        tsum[t] += x;
        __syncthreads();
    }
    int excl = tsum[t] - ts;
    int o0 = excl, o1 = o0 + v0, o2 = o1 + v1, o3 = o2 + v2;
    int n0 = (b << 10) + h0;
    // write per-node offsets, init write cursors, write dis
    wcur[h0] = s + o0; wcur[h0 + 1] = s + o1; wcur[h0 + 2] = s + o2; wcur[h0 + 3] = s + o3;
    if (n0 < N)     { offs[n0]     = s + o0; dis[n0]     = rsqrtf((float)v0 + 1.0f); }
    if (n0 + 1 < N) { offs[n0 + 1] = s + o1; dis[n0 + 1] = rsqrtf((float)v1 + 1.0f); }
    if (n0 + 2 < N) { offs[n0 + 2] = s + o2; dis[n0 + 2] = rsqrtf((float)v2 + 1.0f); }
    if (n0 + 3 < N) { offs[n0 + 3] = s + o3; dis[n0 + 3] = rsqrtf((float)v3 + 1.0f); }
    if (b == 0 && t == 0) offs[N] = E;
    __syncthreads();
    for (int i = s + t; i < e; i += 256) {
        uint en = binned[i];
        int local = (en >> 17) & 1023;
        int p = atomicAdd(&wcur[local], 1);
        csr[p] = (int)(en & 0x1ffffu);
    }
}

// ---------------- GEMM: U = bf16( (A @ W) * dis[row] ) ----------------
__launch_bounds__(256)
__global__ void gemm_scale_kernel(const float* __restrict__ A, const float* __restrict__ W,
                                  const float* __restrict__ dis, uint* __restrict__ U, int N) {
    __shared__ float a_lds[TILE_K][TILE_M + 4];
    __shared__ float w_lds[TILE_K][D + 4];
    int tid = threadIdx.x;
    int m0 = blockIdx.x * TILE_M;
    int tr = (tid >> 4) * 8;
    int tc = (tid & 15) * 8;
    float acc[8][8] = {};

    for (int k0 = 0; k0 < D; k0 += TILE_K) {
        for (int i = tid; i < TILE_K * 32; i += 256) {
            int kk = i >> 5; int cc = (i & 31) << 2;
            float4 wv = *(const float4*)&W[(k0 + kk) * D + cc];
            w_lds[kk][cc] = wv.x; w_lds[kk][cc + 1] = wv.y;
            w_lds[kk][cc + 2] = wv.z; w_lds[kk][cc + 3] = wv.w;
        }
        for (int i = tid; i < 1024; i += 256) {
            int r = i >> 3; int kk = (i & 7) << 2;
            int row = m0 + r;
            float4 av = (row < N) ? *(const float4*)&A[(size_t)row * D + k0 + kk]
                                  : make_float4(0.f, 0.f, 0.f, 0.f);
            a_lds[kk + 0][r] = av.x; a_lds[kk + 1][r] = av.y;
            a_lds[kk + 2][r] = av.z; a_lds[kk + 3][r] = av.w;
        }
        __syncthreads();
#pragma unroll 8
        for (int k = 0; k < TILE_K; k++) {
            float a[8], b[8];
            *(float4*)&a[0] = *(float4*)&a_lds[k][tr];
            *(float4*)&a[4] = *(float4*)&a_lds[k][tr + 4];
            *(float4*)&b[0] = *(float4*)&w_lds[k][tc];
            *(float4*)&b[4] = *(float4*)&w_lds[k][tc + 4];
#pragma unroll
            for (int i = 0; i < 8; i++)
#pragma unroll
                for (int j = 0; j < 8; j++)
                    acc[i][j] = fmaf(a[i], b[j], acc[i][j]);
        }
        __syncthreads();
    }
#pragma unroll
    for (int i = 0; i < 8; i++) {
        int row = m0 + tr + i;
        if (row < N) {
            float s = dis[row];
            uint4 pk;
            pk.x = f2bf(acc[i][0] * s) | (f2bf(acc[i][1] * s) << 16);
            pk.y = f2bf(acc[i][2] * s) | (f2bf(acc[i][3] * s) << 16);
            pk.z = f2bf(acc[i][4] * s) | (f2bf(acc[i][5] * s) << 16);
            pk.w = f2bf(acc[i][6] * s) | (f2bf(acc[i][7] * s) << 16);
            *(uint4*)&U[(size_t)row * 64 + (tc >> 1)] = pk;
        }
    }
}

// ---------------- Aggregation ----------------
__launch_bounds__(256)
__global__ void aggregate_kernel(const uint* __restrict__ U, const int* __restrict__ offs,
                                 const int* __restrict__ csr_src, const float* __restrict__ dis,
                                 const float* __restrict__ bias, float* __restrict__ H, int N) {
    int wave = threadIdx.x >> 6;
    int lane = threadIdx.x & 63;
    int n = blockIdx.x * 4 + wave;
    if (n >= N) return;

    uint self = U[(size_t)n * 64 + lane];
    float accx = bf_lo(self);
    float accy = bf_hi(self);

    int s = offs[n], e = offs[n + 1];
    int i = s;
    for (; i + 3 < e; i += 4) {
        int s0 = csr_src[i], s1 = csr_src[i + 1], s2 = csr_src[i + 2], s3 = csr_src[i + 3];
        uint u0 = U[(size_t)s0 * 64 + lane];
        uint u1 = U[(size_t)s1 * 64 + lane];
        uint u2 = U[(size_t)s2 * 64 + lane];
        uint u3 = U[(size_t)s3 * 64 + lane];
        accx += bf_lo(u0) + bf_lo(u1) + bf_lo(u2) + bf_lo(u3);
        accy += bf_hi(u0) + bf_hi(u1) + bf_hi(u2) + bf_hi(u3);
    }
    for (; i < e; i++) {
        uint u = U[(size_t)csr_src[i] * 64 + lane];
        accx += bf_lo(u);
        accy += bf_hi(u);
    }

    float dn = dis[n];
    float2 b = *(const float2*)&bias[lane * 2];
    float2 o;
    o.x = fmaxf(fmaf(accx, dn, b.x), 0.0f);
    o.y = fmaxf(fmaf(accy, dn, b.y), 0.0f);
    *(float2*)&H[(size_t)n * D + lane * 2] = o;
}

// ---------------- Mean-pool per graph + FC ----------------
__global__ void pool_fc_kernel(const float* __restrict__ H, const int* __restrict__ batch,
                               const float* __restrict__ Wfc, const float* __restrict__ bfc,
                               float* __restrict__ out, int N) {
    int g = blockIdx.x;
    int c = threadIdx.x;
    int lo = 0, hi = N;
    while (lo < hi) { int mid = (lo + hi) >> 1; if (batch[mid] < g) lo = mid + 1; else hi = mid; }
    int st = lo;
    hi = N;
    while (lo < hi) { int mid = (lo + hi) >> 1; if (batch[mid] < g + 1) lo = mid + 1; else hi = mid; }
    int en = lo;
    float sum = 0.f;
    for (int i = st; i < en; i++) sum += H[(size_t)i * D + c];
    float cnt = (float)(en - st);
    if (cnt < 1.f) cnt = 1.f;
    float p = (sum / cnt) * Wfc[c];
    for (int off = 32; off > 0; off >>= 1) p += __shfl_down(p, off);
    __shared__ float red[2];
    if ((c & 63) == 0) red[c >> 6] = p;
    __syncthreads();
    if (c == 0) out[g] = red[0] + red[1] + bfc[0];
}

extern "C" void kernel_launch(void* const* d_in, const int* in_sizes, int n_in,
                              void* d_out, int out_size, void* d_ws, size_t ws_size,
                              hipStream_t stream) {
    const float* x   = (const float*)d_in[0];
    const int* eidx  = (const int*)d_in[1];
    const int* batch = (const int*)d_in[2];
    const float* W1  = (const float*)d_in[3];
    const float* b1  = (const float*)d_in[4];
    const float* W2  = (const float*)d_in[5];
    const float* b2  = (const float*)d_in[6];
    const float* W3  = (const float*)d_in[7];
    const float* b3  = (const float*)d_in[8];
    const float* Wfc = (const float*)d_in[9];
    const float* bfc = (const float*)d_in[10];
    float* out = (float*)d_out;

    int N = in_sizes[2];
    int E = in_sizes[1] / 2;
    int G = out_size;
    int NB = (N + 1023) >> 10;   // <= 128

    const int* src = eidx;
    const int* dst = eidx + E;

    char* ws = (char*)d_ws;
    size_t off = 0;
    auto alloc = [&](size_t bytes) -> void* {
        void* p = ws + off;
        off += (bytes + 255) & ~(size_t)255;
        return p;
    };
    uint* U      = (uint*)alloc((size_t)N * 64 * sizeof(uint));    // bf16 [N,128]
    float* H     = (float*)alloc((size_t)N * D * sizeof(float));
    float* dis   = (float*)alloc((size_t)N * sizeof(float));
    int* offs    = (int*)alloc((size_t)(N + 1) * sizeof(int));
    int* csr     = (int*)alloc((size_t)E * sizeof(int));
    uint* binned = (uint*)alloc((size_t)E * sizeof(uint));
    int* g_cnt   = (int*)alloc(128 * sizeof(int));
    int* bbase   = (int*)alloc(129 * sizeof(int));
    int* cursor  = (int*)alloc(128 * sizeof(int));
    (void)ws_size; (void)n_in;

    hipMemsetAsync(g_cnt, 0, 128 * sizeof(int), stream);

    int cb = (E + CHUNK - 1) / CHUNK;

    bucket_count_kernel<<<cb, 256, 0, stream>>>(dst, g_cnt, E);
    bucket_scan_kernel<<<1, 64, 0, stream>>>(g_cnt, bbase, cursor, NB);
    bin_kernel<<<cb, 256, 0, stream>>>(src, dst, cursor, binned, E);
    bucket_build_kernel<<<NB, 256, 0, stream>>>(binned, bbase, offs, csr, dis, N, E);

    int gb = (N + TILE_M - 1) / TILE_M;
    int ab = (N + 3) / 4;

    gemm_scale_kernel<<<gb, 256, 0, stream>>>(x, W1, dis, U, N);
    aggregate_kernel<<<ab, 256, 0, stream>>>(U, offs, csr, dis, b1, H, N);
    gemm_scale_kernel<<<gb, 256, 0, stream>>>(H, W2, dis, U, N);
    aggregate_kernel<<<ab, 256, 0, stream>>>(U, offs, csr, dis, b2, H, N);
    gemm_scale_kernel<<<gb, 256, 0, stream>>>(H, W3, dis, U, N);
    aggregate_kernel<<<ab, 256, 0, stream>>>(U, offs, csr, dis, b3, H, N);
    pool_fc_kernel<<<G, 128, 0, stream>>>(H, batch, Wfc, bfc, out, N);
}

// Round 4
// 481.276 us; speedup vs baseline: 2.1965x; 1.3342x over previous
//
#include <hip/hip_runtime.h>

#define D 128
#define CHUNK 4096
#define SPAD 36   // uints per LDS row in GEMM stage (32 + 4 pad)

typedef unsigned int uint;
typedef __attribute__((ext_vector_type(8))) short short8;
typedef __attribute__((ext_vector_type(4))) float floatx4;

// ---- bf16 helpers (manual, RNE) ----
__device__ __forceinline__ float bf_lo(uint u) { return __uint_as_float(u << 16); }
__device__ __forceinline__ float bf_hi(uint u) { return __uint_as_float(u & 0xffff0000u); }
__device__ __forceinline__ uint f2bf(float f) {
    uint x = __float_as_uint(f);
    return (x + 0x7fffu + ((x >> 16) & 1u)) >> 16;  // RNE
}

// ================= Bucketed CSR build (unchanged from R3) =================

__global__ void bucket_count_kernel(const int* __restrict__ dst, int* __restrict__ g_cnt, int E) {
    __shared__ int cnt[128];
    int t = threadIdx.x;
    if (t < 128) cnt[t] = 0;
    __syncthreads();
    int s0 = blockIdx.x * CHUNK;
    int e0 = min(s0 + CHUNK, E);
    for (int e = s0 + t; e < e0; e += 256)
        atomicAdd(&cnt[dst[e] >> 10], 1);
    __syncthreads();
    if (t < 128 && cnt[t]) atomicAdd(&g_cnt[t], cnt[t]);
}

__global__ void bucket_scan_kernel(const int* __restrict__ g_cnt, int* __restrict__ base,
                                   int* __restrict__ cursor, int NB) {
    if (threadIdx.x == 0 && blockIdx.x == 0) {
        int acc = 0;
        for (int i = 0; i < NB; i++) {
            base[i] = acc; cursor[i] = acc; acc += g_cnt[i];
        }
        base[NB] = acc;
    }
}

__global__ void bin_kernel(const int* __restrict__ src, const int* __restrict__ dst,
                           int* __restrict__ cursor, uint* __restrict__ binned, int E) {
    __shared__ int cnt[128];
    __shared__ int wcur[128];
    int t = threadIdx.x;
    if (t < 128) cnt[t] = 0;
    __syncthreads();
    int s0 = blockIdx.x * CHUNK;
    int e0 = min(s0 + CHUNK, E);
    for (int e = s0 + t; e < e0; e += 256)
        atomicAdd(&cnt[dst[e] >> 10], 1);
    __syncthreads();
    if (t < 128) {
        int c = cnt[t];
        wcur[t] = c ? atomicAdd(&cursor[t], c) : 0;
    }
    __syncthreads();
    for (int e = s0 + t; e < e0; e += 256) {
        int d = dst[e];
        int b = d >> 10;
        int p = atomicAdd(&wcur[b], 1);
        binned[p] = (uint)src[e] | ((uint)(d & 1023) << 17);
    }
}

__launch_bounds__(256)
__global__ void bucket_build_kernel(const uint* __restrict__ binned, const int* __restrict__ base,
                                    int* __restrict__ offs, int* __restrict__ csr,
                                    float* __restrict__ dis, int N, int E) {
    __shared__ int hist[1024];
    __shared__ int tsum[256];
    __shared__ int wcur[1024];
    int b = blockIdx.x;
    int t = threadIdx.x;
    int s = base[b], e = base[b + 1];
    for (int i = t; i < 1024; i += 256) hist[i] = 0;
    __syncthreads();
    for (int i = s + t; i < e; i += 256)
        atomicAdd(&hist[(binned[i] >> 17) & 1023], 1);
    __syncthreads();
    int h0 = t * 4;
    int v0 = hist[h0], v1 = hist[h0 + 1], v2 = hist[h0 + 2], v3 = hist[h0 + 3];
    int ts = v0 + v1 + v2 + v3;
    tsum[t] = ts;
    __syncthreads();
    for (int off = 1; off < 256; off <<= 1) {
        int x = (t >= off) ? tsum[t - off] : 0;
        __syncthreads();
        tsum[t] += x;
        __syncthreads();
    }
    int excl = tsum[t] - ts;
    int o0 = excl, o1 = o0 + v0, o2 = o1 + v1, o3 = o2 + v2;
    int n0 = (b << 10) + h0;
    wcur[h0] = s + o0; wcur[h0 + 1] = s + o1; wcur[h0 + 2] = s + o2; wcur[h0 + 3] = s + o3;
    if (n0 < N)     { offs[n0]     = s + o0; dis[n0]     = rsqrtf((float)v0 + 1.0f); }
    if (n0 + 1 < N) { offs[n0 + 1] = s + o1; dis[n0 + 1] = rsqrtf((float)v1 + 1.0f); }
    if (n0 + 2 < N) { offs[n0 + 2] = s + o2; dis[n0 + 2] = rsqrtf((float)v2 + 1.0f); }
    if (n0 + 3 < N) { offs[n0 + 3] = s + o3; dis[n0 + 3] = rsqrtf((float)v3 + 1.0f); }
    if (b == 0 && t == 0) offs[N] = E;
    __syncthreads();
    for (int i = s + t; i < e; i += 256) {
        uint en = binned[i];
        int local = (en >> 17) & 1023;
        int p = atomicAdd(&wcur[local], 1);
        csr[p] = (int)(en & 0x1ffffu);
    }
}

// ================= dtype converts =================

// x fp32 [N,128] -> bf16-packed uints [N,64]
__global__ void convert_x_kernel(const float* __restrict__ x, uint* __restrict__ Xb, int n4) {
    int i = blockIdx.x * 256 + threadIdx.x;
    if (i < n4) {
        float4 v = *(const float4*)&x[(size_t)i * 4];
        uint2 o;
        o.x = f2bf(v.x) | (f2bf(v.y) << 16);
        o.y = f2bf(v.z) | (f2bf(v.w) << 16);
        *(uint2*)&Xb[(size_t)i * 2] = o;
    }
}

// W fp32 [k=128][n=128] -> Wt bf16 [n=128][k packed, 64 uints]
__global__ void convert_wt_kernel(const float* __restrict__ W1, const float* __restrict__ W2,
                                  const float* __restrict__ W3, uint* __restrict__ Wt1,
                                  uint* __restrict__ Wt2, uint* __restrict__ Wt3) {
    int gidx = blockIdx.x * 256 + threadIdx.x;   // 3 * 8192
    int w = gidx >> 13, rem = gidx & 8191;
    int n = rem >> 6, kp = rem & 63;
    const float* W = (w == 0) ? W1 : (w == 1) ? W2 : W3;
    uint* Wt = (w == 0) ? Wt1 : (w == 1) ? Wt2 : Wt3;
    Wt[(n << 6) + kp] = f2bf(W[(2 * kp) * 128 + n]) | (f2bf(W[(2 * kp + 1) * 128 + n]) << 16);
}

// ================= MFMA GEMM: U = bf16( (A @ W) * dis[row] ) =================
// A bf16 [N,128] packed uints; Wt bf16 [n][k] packed. 128-row tile/block, K in 2 stages.
__launch_bounds__(256)
__global__ void gemm_mfma_kernel(const uint* __restrict__ Ab, const uint* __restrict__ Wt,
                                 const float* __restrict__ dis, uint* __restrict__ U, int N) {
    __shared__ uint lds[128 * SPAD * 2];
    uint* a_lds = lds;
    uint* w_lds = lds + 128 * SPAD;
    int tid = threadIdx.x;
    int m0 = blockIdx.x * 128;
    int wave = tid >> 6, lane = tid & 63;
    int lm = lane & 15, quad = lane >> 4;

    floatx4 acc[2][8];
#pragma unroll
    for (int i = 0; i < 2; i++)
#pragma unroll
        for (int j = 0; j < 8; j++)
            acc[i][j] = (floatx4){0.f, 0.f, 0.f, 0.f};

    for (int ks = 0; ks < 2; ks++) {
        // stage half-K (64 k = 32 uints per row): 4 uint4 per thread for each of A, W
#pragma unroll
        for (int i = 0; i < 4; i++) {
            int gi = tid + i * 256;
            int row = gi >> 3, c4 = (gi & 7) << 2;
            int grow = m0 + row;
            uint4 av = (grow < N) ? *(const uint4*)&Ab[(size_t)grow * 64 + ks * 32 + c4]
                                  : make_uint4(0u, 0u, 0u, 0u);
            *(uint4*)&a_lds[row * SPAD + c4] = av;
            uint4 wv = *(const uint4*)&Wt[(size_t)row * 64 + ks * 32 + c4];
            *(uint4*)&w_lds[row * SPAD + c4] = wv;
        }
        __syncthreads();
#pragma unroll
        for (int kc = 0; kc < 2; kc++) {
            int ko = kc * 16 + quad * 4;
            short8 b[8];
#pragma unroll
            for (int nt = 0; nt < 8; nt++)
                b[nt] = *(short8*)&w_lds[(nt * 16 + lm) * SPAD + ko];
            short8 a0 = *(short8*)&a_lds[(wave * 32 + lm) * SPAD + ko];
            short8 a1 = *(short8*)&a_lds[(wave * 32 + 16 + lm) * SPAD + ko];
#pragma unroll
            for (int nt = 0; nt < 8; nt++) {
                acc[0][nt] = __builtin_amdgcn_mfma_f32_16x16x32_bf16(a0, b[nt], acc[0][nt], 0, 0, 0);
                acc[1][nt] = __builtin_amdgcn_mfma_f32_16x16x32_bf16(a1, b[nt], acc[1][nt], 0, 0, 0);
            }
        }
        __syncthreads();
    }

    // epilogue: scale by dis, pack bf16, bounce through LDS for coalesced stores
    unsigned short* o_lds = (unsigned short*)lds;  // [128 rows][stride 132 ushorts]
    float dv[2][4];
#pragma unroll
    for (int ms = 0; ms < 2; ms++)
#pragma unroll
        for (int r = 0; r < 4; r++) {
            int row = m0 + wave * 32 + ms * 16 + quad * 4 + r;
            dv[ms][r] = (row < N) ? dis[row] : 0.f;
        }
#pragma unroll
    for (int ms = 0; ms < 2; ms++)
#pragma unroll
        for (int nt = 0; nt < 8; nt++)
#pragma unroll
            for (int r = 0; r < 4; r++) {
                int row = wave * 32 + ms * 16 + quad * 4 + r;   // C/D: row=(lane>>4)*4+reg
                int col = nt * 16 + lm;                          // col=lane&15
                o_lds[row * 132 + col] = (unsigned short)f2bf(acc[ms][nt][r] * dv[ms][r]);
            }
    __syncthreads();
#pragma unroll
    for (int i = 0; i < 16; i++) {
        int gi = tid + i * 256;          // 4096 uint2 total
        int row = gi >> 5, c2 = gi & 31;
        int grow = m0 + row;
        if (grow < N) {
            uint2 v = *(uint2*)&lds[row * 66 + c2 * 2];
            *(uint2*)&U[(size_t)grow * 64 + c2 * 2] = v;
        }
    }
}

// ================= Aggregation: H = bf16(relu(dis*(u_self + sum u_src) + b)) =================
__launch_bounds__(256)
__global__ void aggregate_kernel(const uint* __restrict__ U, const int* __restrict__ offs,
                                 const int* __restrict__ csr_src, const float* __restrict__ dis,
                                 const float* __restrict__ bias, uint* __restrict__ H, int N) {
    int wave = threadIdx.x >> 6;
    int lane = threadIdx.x & 63;
    int n = blockIdx.x * 4 + wave;
    if (n >= N) return;

    uint self = U[(size_t)n * 64 + lane];
    float accx = bf_lo(self);
    float accy = bf_hi(self);

    int s = offs[n], e = offs[n + 1];
    int i = s;
    for (; i + 3 < e; i += 4) {
        int s0 = csr_src[i], s1 = csr_src[i + 1], s2 = csr_src[i + 2], s3 = csr_src[i + 3];
        uint u0 = U[(size_t)s0 * 64 + lane];
        uint u1 = U[(size_t)s1 * 64 + lane];
        uint u2 = U[(size_t)s2 * 64 + lane];
        uint u3 = U[(size_t)s3 * 64 + lane];
        accx += bf_lo(u0) + bf_lo(u1) + bf_lo(u2) + bf_lo(u3);
        accy += bf_hi(u0) + bf_hi(u1) + bf_hi(u2) + bf_hi(u3);
    }
    for (; i < e; i++) {
        uint u = U[(size_t)csr_src[i] * 64 + lane];
        accx += bf_lo(u);
        accy += bf_hi(u);
    }

    float dn = dis[n];
    float2 b = *(const float2*)&bias[lane * 2];
    float ox = fmaxf(fmaf(accx, dn, b.x), 0.0f);
    float oy = fmaxf(fmaf(accy, dn, b.y), 0.0f);
    H[(size_t)n * 64 + lane] = f2bf(ox) | (f2bf(oy) << 16);
}

// ================= Mean-pool per graph + FC (bf16 H) =================
__launch_bounds__(512)
__global__ void pool_fc_kernel(const uint* __restrict__ H, const int* __restrict__ batch,
                               const float* __restrict__ Wfc, const float* __restrict__ bfc,
                               float* __restrict__ out, int N) {
    __shared__ float2 red[512];
    int g = blockIdx.x;
    int t = threadIdx.x;
    int rid = t >> 6, lane = t & 63;

    int lo = 0, hi = N;
    while (lo < hi) { int mid = (lo + hi) >> 1; if (batch[mid] < g) lo = mid + 1; else hi = mid; }
    int st = lo;
    hi = N;
    while (lo < hi) { int mid = (lo + hi) >> 1; if (batch[mid] < g + 1) lo = mid + 1; else hi = mid; }
    int en = lo;

    float ax = 0.f, ay = 0.f;
    for (int r = st + rid; r < en; r += 8) {
        uint u = H[(size_t)r * 64 + lane];
        ax += bf_lo(u);
        ay += bf_hi(u);
    }
    red[t] = make_float2(ax, ay);
    __syncthreads();
    if (rid == 0) {
        float2 sv = red[lane];
#pragma unroll
        for (int i = 1; i < 8; i++) { sv.x += red[i * 64 + lane].x; sv.y += red[i * 64 + lane].y; }
        float cnt = fmaxf((float)(en - st), 1.0f);
        float p = (sv.x / cnt) * Wfc[lane * 2] + (sv.y / cnt) * Wfc[lane * 2 + 1];
        for (int off = 32; off > 0; off >>= 1) p += __shfl_down(p, off);
        if (lane == 0) out[g] = p + bfc[0];
    }
}

extern "C" void kernel_launch(void* const* d_in, const int* in_sizes, int n_in,
                              void* d_out, int out_size, void* d_ws, size_t ws_size,
                              hipStream_t stream) {
    const float* x   = (const float*)d_in[0];
    const int* eidx  = (const int*)d_in[1];
    const int* batch = (const int*)d_in[2];
    const float* W1  = (const float*)d_in[3];
    const float* b1  = (const float*)d_in[4];
    const float* W2  = (const float*)d_in[5];
    const float* b2  = (const float*)d_in[6];
    const float* W3  = (const float*)d_in[7];
    const float* b3  = (const float*)d_in[8];
    const float* Wfc = (const float*)d_in[9];
    const float* bfc = (const float*)d_in[10];
    float* out = (float*)d_out;

    int N = in_sizes[2];
    int E = in_sizes[1] / 2;
    int G = out_size;
    int NB = (N + 1023) >> 10;

    const int* src = eidx;
    const int* dst = eidx + E;

    char* ws = (char*)d_ws;
    size_t off = 0;
    auto alloc = [&](size_t bytes) -> void* {
        void* p = ws + off;
        off += (bytes + 255) & ~(size_t)255;
        return p;
    };
    uint* U      = (uint*)alloc((size_t)N * 64 * sizeof(uint));   // bf16 [N,128]
    uint* Hb     = (uint*)alloc((size_t)N * 64 * sizeof(uint));   // bf16 [N,128]
    uint* Xb     = (uint*)alloc((size_t)N * 64 * sizeof(uint));   // bf16 [N,128]
    uint* Wt1    = (uint*)alloc(8192 * sizeof(uint));
    uint* Wt2    = (uint*)alloc(8192 * sizeof(uint));
    uint* Wt3    = (uint*)alloc(8192 * sizeof(uint));
    float* dis   = (float*)alloc((size_t)N * sizeof(float));
    int* offs    = (int*)alloc((size_t)(N + 1) * sizeof(int));
    int* csr     = (int*)alloc((size_t)E * sizeof(int));
    uint* binned = (uint*)alloc((size_t)E * sizeof(uint));
    int* g_cnt   = (int*)alloc(128 * sizeof(int));
    int* bbase   = (int*)alloc(129 * sizeof(int));
    int* cursor  = (int*)alloc(128 * sizeof(int));
    (void)ws_size; (void)n_in;

    hipMemsetAsync(g_cnt, 0, 128 * sizeof(int), stream);

    int cb = (E + CHUNK - 1) / CHUNK;

    bucket_count_kernel<<<cb, 256, 0, stream>>>(dst, g_cnt, E);
    bucket_scan_kernel<<<1, 64, 0, stream>>>(g_cnt, bbase, cursor, NB);
    bin_kernel<<<cb, 256, 0, stream>>>(src, dst, cursor, binned, E);
    bucket_build_kernel<<<NB, 256, 0, stream>>>(binned, bbase, offs, csr, dis, N, E);

    int n4 = N * 32;
    convert_x_kernel<<<(n4 + 255) / 256, 256, 0, stream>>>(x, Xb, n4);
    convert_wt_kernel<<<96, 256, 0, stream>>>(W1, W2, W3, Wt1, Wt2, Wt3);

    int gb = (N + 127) / 128;
    int ab = (N + 3) / 4;

    gemm_mfma_kernel<<<gb, 256, 0, stream>>>(Xb, Wt1, dis, U, N);
    aggregate_kernel<<<ab, 256, 0, stream>>>(U, offs, csr, dis, b1, Hb, N);
    gemm_mfma_kernel<<<gb, 256, 0, stream>>>(Hb, Wt2, dis, U, N);
    aggregate_kernel<<<ab, 256, 0, stream>>>(U, offs, csr, dis, b2, Hb, N);
    gemm_mfma_kernel<<<gb, 256, 0, stream>>>(Hb, Wt3, dis, U, N);
    aggregate_kernel<<<ab, 256, 0, stream>>>(U, offs, csr, dis, b3, Hb, N);
    pool_fc_kernel<<<G, 512, 0, stream>>>(Hb, batch, Wfc, bfc, out, N);
}

// Round 5
// 438.646 us; speedup vs baseline: 2.4099x; 1.0972x over previous
//
#include <hip/hip_runtime.h>

#define D 128
#define CHUNK 4096
#define SPAD 36   // uints per LDS row in GEMM stage (32 + 4 pad)

typedef unsigned int uint;
typedef __attribute__((ext_vector_type(8))) short short8;
typedef __attribute__((ext_vector_type(4))) float floatx4;

// ---- bf16 helpers (manual, RNE) ----
__device__ __forceinline__ float bf_lo(uint u) { return __uint_as_float(u << 16); }
__device__ __forceinline__ float bf_hi(uint u) { return __uint_as_float(u & 0xffff0000u); }
__device__ __forceinline__ uint f2bf(float f) {
    uint x = __float_as_uint(f);
    return (x + 0x7fffu + ((x >> 16) & 1u)) >> 16;  // RNE
}

// ================= Bucketed CSR build (single-pass binning, fixed-CAP windows) =================
// bucket = dst >> 10; binned entry = src | (local_dst << 17)

__global__ void init_cursor_kernel(int* __restrict__ cursor, int NB, int CAP) {
    int b = threadIdx.x + blockIdx.x * 128;
    if (b < NB) cursor[b] = b * CAP;
}

__global__ void bin_kernel(const int* __restrict__ src, const int* __restrict__ dst,
                           int* __restrict__ cursor, uint* __restrict__ binned, int E) {
    __shared__ int cnt[128];
    __shared__ int wcur[128];
    int t = threadIdx.x;
    if (t < 128) cnt[t] = 0;
    __syncthreads();
    int s0 = blockIdx.x * CHUNK;
    int e0 = min(s0 + CHUNK, E);
    for (int e = s0 + t; e < e0; e += 256)
        atomicAdd(&cnt[dst[e] >> 10], 1);
    __syncthreads();
    if (t < 128) {
        int c = cnt[t];
        wcur[t] = c ? atomicAdd(&cursor[t], c) : 0;
    }
    __syncthreads();
    for (int e = s0 + t; e < e0; e += 256) {
        int d = dst[e];
        int b = d >> 10;
        int p = atomicAdd(&wcur[b], 1);
        binned[p] = (uint)src[e] | ((uint)(d & 1023) << 17);
    }
}

// one block per bucket: local hist -> scan -> offs/oend/dis write -> windowed csr scatter
__launch_bounds__(256)
__global__ void bucket_build_kernel(const uint* __restrict__ binned, const int* __restrict__ cursor,
                                    int* __restrict__ offs, int* __restrict__ oend,
                                    int* __restrict__ csr, float* __restrict__ dis,
                                    int N, int CAP) {
    __shared__ int hist[1024];
    __shared__ int tsum[256];
    __shared__ int wcur[1024];
    int b = blockIdx.x;
    int t = threadIdx.x;
    int s = b * CAP;
    int e = cursor[b];            // final cursor = window end after bin
    for (int i = t; i < 1024; i += 256) hist[i] = 0;
    __syncthreads();
    for (int i = s + t; i < e; i += 256)
        atomicAdd(&hist[(binned[i] >> 17) & 1023], 1);
    __syncthreads();
    int h0 = t * 4;
    int v0 = hist[h0], v1 = hist[h0 + 1], v2 = hist[h0 + 2], v3 = hist[h0 + 3];
    int ts = v0 + v1 + v2 + v3;
    tsum[t] = ts;
    __syncthreads();
    for (int off = 1; off < 256; off <<= 1) {
        int x = (t >= off) ? tsum[t - off] : 0;
        __syncthreads();
        tsum[t] += x;
        __syncthreads();
    }
    int excl = tsum[t] - ts;
    int o0 = excl, o1 = o0 + v0, o2 = o1 + v1, o3 = o2 + v2;
    int n0 = (b << 10) + h0;
    wcur[h0] = s + o0; wcur[h0 + 1] = s + o1; wcur[h0 + 2] = s + o2; wcur[h0 + 3] = s + o3;
    if (n0 < N)     { offs[n0]     = s + o0; oend[n0]     = s + o0 + v0; dis[n0]     = rsqrtf((float)v0 + 1.0f); }
    if (n0 + 1 < N) { offs[n0 + 1] = s + o1; oend[n0 + 1] = s + o1 + v1; dis[n0 + 1] = rsqrtf((float)v1 + 1.0f); }
    if (n0 + 2 < N) { offs[n0 + 2] = s + o2; oend[n0 + 2] = s + o2 + v2; dis[n0 + 2] = rsqrtf((float)v2 + 1.0f); }
    if (n0 + 3 < N) { offs[n0 + 3] = s + o3; oend[n0 + 3] = s + o3 + v3; dis[n0 + 3] = rsqrtf((float)v3 + 1.0f); }
    __syncthreads();
    for (int i = s + t; i < e; i += 256) {
        uint en = binned[i];
        int local = (en >> 17) & 1023;
        int p = atomicAdd(&wcur[local], 1);
        csr[p] = (int)(en & 0x1ffffu);
    }
}

// ================= W convert =================
// W fp32 [k=128][n=128] -> Wt bf16 [n=128][k packed, 64 uints]
__global__ void convert_wt_kernel(const float* __restrict__ W1, const float* __restrict__ W2,
                                  const float* __restrict__ W3, uint* __restrict__ Wt1,
                                  uint* __restrict__ Wt2, uint* __restrict__ Wt3) {
    int gidx = blockIdx.x * 256 + threadIdx.x;   // 3 * 8192
    int w = gidx >> 13, rem = gidx & 8191;
    int n = rem >> 6, kp = rem & 63;
    const float* W = (w == 0) ? W1 : (w == 1) ? W2 : W3;
    uint* Wt = (w == 0) ? Wt1 : (w == 1) ? Wt2 : Wt3;
    Wt[(n << 6) + kp] = f2bf(W[(2 * kp) * 128 + n]) | (f2bf(W[(2 * kp + 1) * 128 + n]) << 16);
}

// ================= MFMA GEMM: U = bf16( (A @ W) * dis[row] ) =================
// F32A: A is fp32 [N,128] (layer 1, converted during staging); else bf16-packed [N,64].
template <bool F32A>
__launch_bounds__(256)
__global__ void gemm_mfma_kernel(const void* __restrict__ Aptr, const uint* __restrict__ Wt,
                                 const float* __restrict__ dis, uint* __restrict__ U, int N) {
    __shared__ uint lds[128 * SPAD * 2];
    uint* a_lds = lds;
    uint* w_lds = lds + 128 * SPAD;
    int tid = threadIdx.x;
    int m0 = blockIdx.x * 128;
    int wave = tid >> 6, lane = tid & 63;
    int lm = lane & 15, quad = lane >> 4;

    floatx4 acc[2][8];
#pragma unroll
    for (int i = 0; i < 2; i++)
#pragma unroll
        for (int j = 0; j < 8; j++)
            acc[i][j] = (floatx4){0.f, 0.f, 0.f, 0.f};

    for (int ks = 0; ks < 2; ks++) {
        if (F32A) {
            const float* Af = (const float*)Aptr;
#pragma unroll
            for (int i = 0; i < 8; i++) {
                int gi = tid + i * 256;           // 2048 = 128 rows x 16 float4
                int row = gi >> 4, j = gi & 15;
                int grow = m0 + row;
                float4 v = (grow < N) ? *(const float4*)&Af[(size_t)grow * 128 + ks * 64 + j * 4]
                                      : make_float4(0.f, 0.f, 0.f, 0.f);
                uint2 o;
                o.x = f2bf(v.x) | (f2bf(v.y) << 16);
                o.y = f2bf(v.z) | (f2bf(v.w) << 16);
                *(uint2*)&a_lds[row * SPAD + j * 2] = o;
            }
        } else {
            const uint* Ab = (const uint*)Aptr;
#pragma unroll
            for (int i = 0; i < 4; i++) {
                int gi = tid + i * 256;           // 1024 = 128 rows x 8 uint4
                int row = gi >> 3, c4 = (gi & 7) << 2;
                int grow = m0 + row;
                uint4 av = (grow < N) ? *(const uint4*)&Ab[(size_t)grow * 64 + ks * 32 + c4]
                                      : make_uint4(0u, 0u, 0u, 0u);
                *(uint4*)&a_lds[row * SPAD + c4] = av;
            }
        }
#pragma unroll
        for (int i = 0; i < 4; i++) {
            int gi = tid + i * 256;
            int row = gi >> 3, c4 = (gi & 7) << 2;
            *(uint4*)&w_lds[row * SPAD + c4] = *(const uint4*)&Wt[(size_t)row * 64 + ks * 32 + c4];
        }
        __syncthreads();
#pragma unroll
        for (int kc = 0; kc < 2; kc++) {
            int ko = kc * 16 + quad * 4;
            short8 b[8];
#pragma unroll
            for (int nt = 0; nt < 8; nt++)
                b[nt] = *(short8*)&w_lds[(nt * 16 + lm) * SPAD + ko];
            short8 a0 = *(short8*)&a_lds[(wave * 32 + lm) * SPAD + ko];
            short8 a1 = *(short8*)&a_lds[(wave * 32 + 16 + lm) * SPAD + ko];
#pragma unroll
            for (int nt = 0; nt < 8; nt++) {
                acc[0][nt] = __builtin_amdgcn_mfma_f32_16x16x32_bf16(a0, b[nt], acc[0][nt], 0, 0, 0);
                acc[1][nt] = __builtin_amdgcn_mfma_f32_16x16x32_bf16(a1, b[nt], acc[1][nt], 0, 0, 0);
            }
        }
        __syncthreads();
    }

    // epilogue: scale by dis, pack bf16, bounce through LDS for coalesced stores
    unsigned short* o_lds = (unsigned short*)lds;  // [128 rows][stride 132 ushorts]
    float dv[2][4];
#pragma unroll
    for (int ms = 0; ms < 2; ms++)
#pragma unroll
        for (int r = 0; r < 4; r++) {
            int row = m0 + wave * 32 + ms * 16 + quad * 4 + r;
            dv[ms][r] = (row < N) ? dis[row] : 0.f;
        }
#pragma unroll
    for (int ms = 0; ms < 2; ms++)
#pragma unroll
        for (int nt = 0; nt < 8; nt++)
#pragma unroll
            for (int r = 0; r < 4; r++) {
                int row = wave * 32 + ms * 16 + quad * 4 + r;   // C/D: row=(lane>>4)*4+reg
                int col = nt * 16 + lm;                          // col=lane&15
                o_lds[row * 132 + col] = (unsigned short)f2bf(acc[ms][nt][r] * dv[ms][r]);
            }
    __syncthreads();
#pragma unroll
    for (int i = 0; i < 16; i++) {
        int gi = tid + i * 256;          // 4096 uint2 total
        int row = gi >> 5, c2 = gi & 31;
        int grow = m0 + row;
        if (grow < N) {
            uint2 v = *(uint2*)&lds[row * 66 + c2 * 2];
            *(uint2*)&U[(size_t)grow * 64 + c2 * 2] = v;
        }
    }
}

// ================= Aggregation: H = bf16(relu(dis*(u_self + sum u_src) + b)) =================
__launch_bounds__(256)
__global__ void aggregate_kernel(const uint* __restrict__ U, const int* __restrict__ offs,
                                 const int* __restrict__ oend, const int* __restrict__ csr_src,
                                 const float* __restrict__ dis, const float* __restrict__ bias,
                                 uint* __restrict__ H, int N) {
    int wave = threadIdx.x >> 6;
    int lane = threadIdx.x & 63;
    int n = blockIdx.x * 4 + wave;
    if (n >= N) return;

    uint self = U[(size_t)n * 64 + lane];
    float accx = bf_lo(self);
    float accy = bf_hi(self);

    int s = offs[n], e = oend[n];
    int i = s;
    for (; i + 7 < e; i += 8) {
        int s0 = csr_src[i],     s1 = csr_src[i + 1], s2 = csr_src[i + 2], s3 = csr_src[i + 3];
        int s4 = csr_src[i + 4], s5 = csr_src[i + 5], s6 = csr_src[i + 6], s7 = csr_src[i + 7];
        uint u0 = U[(size_t)s0 * 64 + lane];
        uint u1 = U[(size_t)s1 * 64 + lane];
        uint u2 = U[(size_t)s2 * 64 + lane];
        uint u3 = U[(size_t)s3 * 64 + lane];
        uint u4 = U[(size_t)s4 * 64 + lane];
        uint u5 = U[(size_t)s5 * 64 + lane];
        uint u6 = U[(size_t)s6 * 64 + lane];
        uint u7 = U[(size_t)s7 * 64 + lane];
        accx += bf_lo(u0) + bf_lo(u1) + bf_lo(u2) + bf_lo(u3)
              + bf_lo(u4) + bf_lo(u5) + bf_lo(u6) + bf_lo(u7);
        accy += bf_hi(u0) + bf_hi(u1) + bf_hi(u2) + bf_hi(u3)
              + bf_hi(u4) + bf_hi(u5) + bf_hi(u6) + bf_hi(u7);
    }
    for (; i + 3 < e; i += 4) {
        int s0 = csr_src[i], s1 = csr_src[i + 1], s2 = csr_src[i + 2], s3 = csr_src[i + 3];
        uint u0 = U[(size_t)s0 * 64 + lane];
        uint u1 = U[(size_t)s1 * 64 + lane];
        uint u2 = U[(size_t)s2 * 64 + lane];
        uint u3 = U[(size_t)s3 * 64 + lane];
        accx += bf_lo(u0) + bf_lo(u1) + bf_lo(u2) + bf_lo(u3);
        accy += bf_hi(u0) + bf_hi(u1) + bf_hi(u2) + bf_hi(u3);
    }
    for (; i < e; i++) {
        uint u = U[(size_t)csr_src[i] * 64 + lane];
        accx += bf_lo(u);
        accy += bf_hi(u);
    }

    float dn = dis[n];
    float2 b = *(const float2*)&bias[lane * 2];
    float ox = fmaxf(fmaf(accx, dn, b.x), 0.0f);
    float oy = fmaxf(fmaf(accy, dn, b.y), 0.0f);
    H[(size_t)n * 64 + lane] = f2bf(ox) | (f2bf(oy) << 16);
}

// ================= Mean-pool per graph + FC (bf16 H) =================
__launch_bounds__(512)
__global__ void pool_fc_kernel(const uint* __restrict__ H, const int* __restrict__ batch,
                               const float* __restrict__ Wfc, const float* __restrict__ bfc,
                               float* __restrict__ out, int N) {
    __shared__ float2 red[512];
    int g = blockIdx.x;
    int t = threadIdx.x;
    int rid = t >> 6, lane = t & 63;

    int lo = 0, hi = N;
    while (lo < hi) { int mid = (lo + hi) >> 1; if (batch[mid] < g) lo = mid + 1; else hi = mid; }
    int st = lo;
    hi = N;
    while (lo < hi) { int mid = (lo + hi) >> 1; if (batch[mid] < g + 1) lo = mid + 1; else hi = mid; }
    int en = lo;

    float ax = 0.f, ay = 0.f;
    for (int r = st + rid; r < en; r += 8) {
        uint u = H[(size_t)r * 64 + lane];
        ax += bf_lo(u);
        ay += bf_hi(u);
    }
    red[t] = make_float2(ax, ay);
    __syncthreads();
    if (rid == 0) {
        float2 sv = red[lane];
#pragma unroll
        for (int i = 1; i < 8; i++) { sv.x += red[i * 64 + lane].x; sv.y += red[i * 64 + lane].y; }
        float cnt = fmaxf((float)(en - st), 1.0f);
        float p = (sv.x / cnt) * Wfc[lane * 2] + (sv.y / cnt) * Wfc[lane * 2 + 1];
        for (int off = 32; off > 0; off >>= 1) p += __shfl_down(p, off);
        if (lane == 0) out[g] = p + bfc[0];
    }
}

extern "C" void kernel_launch(void* const* d_in, const int* in_sizes, int n_in,
                              void* d_out, int out_size, void* d_ws, size_t ws_size,
                              hipStream_t stream) {
    const float* x   = (const float*)d_in[0];
    const int* eidx  = (const int*)d_in[1];
    const int* batch = (const int*)d_in[2];
    const float* W1  = (const float*)d_in[3];
    const float* b1  = (const float*)d_in[4];
    const float* W2  = (const float*)d_in[5];
    const float* b2  = (const float*)d_in[6];
    const float* W3  = (const float*)d_in[7];
    const float* b3  = (const float*)d_in[8];
    const float* Wfc = (const float*)d_in[9];
    const float* bfc = (const float*)d_in[10];
    float* out = (float*)d_out;

    int N = in_sizes[2];
    int E = in_sizes[1] / 2;
    int G = out_size;
    int NB = (N + 1023) >> 10;                 // <= 128
    int CAP = E / NB + 2048;                   // per-bucket window (uniform dst: ~16 sigma slack)

    const int* src = eidx;
    const int* dst = eidx + E;

    char* ws = (char*)d_ws;
    size_t off = 0;
    auto alloc = [&](size_t bytes) -> void* {
        void* p = ws + off;
        off += (bytes + 255) & ~(size_t)255;
        return p;
    };
    size_t winsz = (size_t)NB * CAP;
    uint* U      = (uint*)alloc((size_t)N * 64 * sizeof(uint));   // bf16 [N,128]
    uint* Hb     = (uint*)alloc((size_t)N * 64 * sizeof(uint));   // bf16 [N,128]
    uint* Wt1    = (uint*)alloc(8192 * sizeof(uint));
    uint* Wt2    = (uint*)alloc(8192 * sizeof(uint));
    uint* Wt3    = (uint*)alloc(8192 * sizeof(uint));
    float* dis   = (float*)alloc((size_t)N * sizeof(float));
    int* offs    = (int*)alloc((size_t)N * sizeof(int));
    int* oend    = (int*)alloc((size_t)N * sizeof(int));
    int* csr     = (int*)alloc(winsz * sizeof(int));
    uint* binned = (uint*)alloc(winsz * sizeof(uint));
    int* cursor  = (int*)alloc(256 * sizeof(int));
    (void)ws_size; (void)n_in;

    int cb = (E + CHUNK - 1) / CHUNK;

    init_cursor_kernel<<<1, 128, 0, stream>>>(cursor, NB, CAP);
    bin_kernel<<<cb, 256, 0, stream>>>(src, dst, cursor, binned, E);
    bucket_build_kernel<<<NB, 256, 0, stream>>>(binned, cursor, offs, oend, csr, dis, N, CAP);

    convert_wt_kernel<<<96, 256, 0, stream>>>(W1, W2, W3, Wt1, Wt2, Wt3);

    int gb = (N + 127) / 128;
    int ab = (N + 3) / 4;

    gemm_mfma_kernel<true><<<gb, 256, 0, stream>>>(x, Wt1, dis, U, N);
    aggregate_kernel<<<ab, 256, 0, stream>>>(U, offs, oend, csr, dis, b1, Hb, N);
    gemm_mfma_kernel<false><<<gb, 256, 0, stream>>>(Hb, Wt2, dis, U, N);
    aggregate_kernel<<<ab, 256, 0, stream>>>(U, offs, oend, csr, dis, b2, Hb, N);
    gemm_mfma_kernel<false><<<gb, 256, 0, stream>>>(Hb, Wt3, dis, U, N);
    aggregate_kernel<<<ab, 256, 0, stream>>>(U, offs, oend, csr, dis, b3, Hb, N);
    pool_fc_kernel<<<G, 512, 0, stream>>>(Hb, batch, Wfc, bfc, out, N);
}